// Round 18
// baseline (3562.829 us; speedup 1.0000x reference)
//
#include <hip/hip_runtime.h>
#include <hip/hip_bf16.h>

typedef __bf16 bf16x8 __attribute__((ext_vector_type(8)));
typedef unsigned short u16x8 __attribute__((ext_vector_type(8)));
typedef float f32x4 __attribute__((ext_vector_type(4)));

constexpr int TT = 64;   // timesteps
constexpr int BB = 64;   // batch
constexpr int SS = 128;  // memory length
constexpr int HH = 512;  // hidden
constexpr int GG = 2048; // 4*H

// weight sizes (elements); hi at [0], lo at [N]
constexpr int NW0E = 2048 * 512;
constexpr int NW0R = 2048 * 1024;
constexpr int NW1  = 2048 * 512;
constexpr int NWO  = 512 * 1024;   // WoutT f32 element count
constexpr int NWI  = 512 * 512;

struct P {
  const int* tok; const float* mbank; const int* len;
  const float* h0_in; const float* c0_in; const float* emb;
  const float* w_ih0; const float* w_hh0; const float* b_ih0; const float* b_hh0;
  const float* w_ih1; const float* w_hh1; const float* b_ih1; const float* b_hh1;
  const float* w_in; const float* w_out;
  float* out_dec; float* out_attn; float* out_hf; float* out_cf;
  unsigned short *W0E, *W0R, *Wih1, *Whh1, *WinT;
  float *WoutT;                           // [1024][512] f32 transposed
  float *EGb;                             // f32: score-path precision
  float *Mw;
  float *b0, *b1, *h0buf, *h1s, *c0s, *c1s, *feed, *part1, *ctx, *scg;
  unsigned int* flag;  // [0..63] score, [64..127] ctx, [128 + g*128 + u] barrier
};

__device__ __forceinline__ unsigned short f2bf(float f) {
  unsigned int u = __builtin_bit_cast(unsigned int, f);
  return (unsigned short)((u + 0x7fffu + ((u >> 16) & 1u)) >> 16);
}
__device__ __forceinline__ float bf2f(unsigned short h) {
  return __builtin_bit_cast(float, ((unsigned int)h) << 16);
}
__device__ __forceinline__ bf16x8 ldb(const unsigned short* p) {
  return __builtin_bit_cast(bf16x8, *(const u16x8*)p);
}
__device__ __forceinline__ f32x4 mfma_(bf16x8 a, bf16x8 b, f32x4 c) {
  return __builtin_amdgcn_mfma_f32_16x16x32_bf16(a, b, c, 0, 0, 0);
}
__device__ __forceinline__ float sigm(float x) { return 1.f / (1.f + __expf(-x)); }
__device__ __forceinline__ f32x4 zero4() { f32x4 z = {0.f, 0.f, 0.f, 0.f}; return z; }

#define ATL(pp) __hip_atomic_load((pp), __ATOMIC_RELAXED, __HIP_MEMORY_SCOPE_AGENT)
#define ATS(pp, vv) __hip_atomic_store((pp), (vv), __ATOMIC_RELAXED, __HIP_MEMORY_SCOPE_AGENT)
#define ATA(pp, vv) __hip_atomic_fetch_add((pp), (vv), __ATOMIC_RELAXED, __HIP_MEMORY_SCOPE_AGENT)

__device__ __forceinline__ void splitA(const float* s, bf16x8& hi, bf16x8& lo) {
  float4 a0 = *(const float4*)s;
  float4 a1 = *(const float4*)(s + 4);
  float v[8] = {a0.x, a0.y, a0.z, a0.w, a1.x, a1.y, a1.z, a1.w};
  u16x8 h, l;
#pragma unroll
  for (int j = 0; j < 8; ++j) {
    unsigned short hb = f2bf(v[j]);
    h[j] = hb;
    l[j] = f2bf(v[j] - bf2f(hb));
  }
  hi = __builtin_bit_cast(bf16x8, h);
  lo = __builtin_bit_cast(bf16x8, l);
}
__device__ __forceinline__ f32x4 mfma3(bf16x8 ah, bf16x8 al, bf16x8 bh, bf16x8 bl, f32x4 c) {
  c = mfma_(al, bh, c);
  c = mfma_(ah, bl, c);
  c = mfma_(ah, bh, c);
  return c;
}

// ---------------- prep: weight split / transpose / state init ----------------
__global__ void prep_weights(P p) {
  constexpr int TOT = NW0E + NW0R + NW1 + NW1 + NWO + NWI + 2048 + 2048 +
                      32768 * 5 + 8192 + 1024;
  for (int i = blockIdx.x * blockDim.x + threadIdx.x; i < TOT;
       i += gridDim.x * blockDim.x) {
    int j = i;
    float v; unsigned short* dst; int N;
    if (j < NW0E) {              // emb part of w_ih0: [2048][512]
      int n = j >> 9, k = j & 511;
      v = p.w_ih0[n * 1024 + k];
      dst = p.W0E; N = NW0E; goto split;
    }
    j -= NW0E;
    if (j < NW0R) {              // [feed | h] : [2048][1024]
      int n = j >> 10, k = j & 1023;
      v = (k < 512) ? p.w_ih0[n * 1024 + 512 + k] : p.w_hh0[n * 512 + (k - 512)];
      dst = p.W0R; N = NW0R; goto split;
    }
    j -= NW0R;
    if (j < NW1) { v = p.w_ih1[j]; dst = p.Wih1; N = NW1; goto split; }
    j -= NW1;
    if (j < NW1) { v = p.w_hh1[j]; dst = p.Whh1; N = NW1; goto split; }
    j -= NW1;
    if (j < NWO) {               // WoutT[k][n] = w_out[n][k]  (f32)
      int k = j >> 9, n = j & 511;
      p.WoutT[j] = p.w_out[n * 1024 + k];
      continue;
    }
    j -= NWO;
    if (j < NWI) {               // WinT[n][k] = w_in[k][n]
      int n = j >> 9, q = j & 511;
      v = p.w_in[q * 512 + n];
      dst = p.WinT; N = NWI; goto split;
    }
    j -= NWI;
    if (j < 2048) { p.b0[j] = p.b_ih0[j] + p.b_hh0[j]; continue; }
    j -= 2048;
    if (j < 2048) { p.b1[j] = p.b_ih1[j] + p.b_hh1[j]; continue; }
    j -= 2048;
    if (j < 32768) { p.h0buf[j] = p.h0_in[j]; continue; }
    j -= 32768;
    if (j < 32768) { p.h1s[j] = p.h0_in[32768 + j]; continue; }
    j -= 32768;
    if (j < 32768) { p.c0s[j] = p.c0_in[j]; continue; }
    j -= 32768;
    if (j < 32768) { p.c1s[j] = p.c0_in[32768 + j]; continue; }
    j -= 32768;
    if (j < 32768) { p.feed[j] = 0.f; continue; }
    j -= 32768;
    if (j < 8192) { p.scg[j] = 0.f; continue; }
    j -= 8192;
    p.flag[j] = 0u;
    continue;
  split:
    {
      unsigned short hb = f2bf(v);
      dst[j] = hb;
      dst[N + j] = f2bf(v - bf2f(hb));
    }
  }
}

// ---------------- prep: Mw[b,s,n] = sum_k M[b,s,k] * w_in[k,n]  (f32) ----------------
__global__ void prep_mw(P p) {
  const int wg = blockIdx.x;             // 4096 = 128 m-blocks x 32 n-tiles
  const int bm = wg & 127, bn = wg >> 7;
  const int tid = threadIdx.x, wave = tid >> 6, lane = tid & 63;
  const int arow = lane & 15, kq = (lane >> 4) * 8;
  const int m0 = bm * 64 + wave * 16;
  const int n0 = bn * 16;
  const float* A = p.mbank + (size_t)(m0 + arow) * HH;
  const unsigned short* Bp = p.WinT + (size_t)(n0 + arow) * HH + kq;
  f32x4 acc = zero4();
  for (int kk = 0; kk < HH; kk += 32) {
    bf16x8 ah, al;
    splitA(A + kk + kq, ah, al);
    acc = mfma3(ah, al, ldb(Bp + kk), ldb(Bp + NWI + kk), acc);
  }
  const int r0 = m0 + (lane >> 4) * 4;
#pragma unroll
  for (int r = 0; r < 4; ++r)
    p.Mw[(size_t)(r0 + r) * HH + n0 + arow] = acc[r];
}

// ---------------- prep: EGb[t*64+b, n] = emb[tok] @ W0E^T + b0  (f32) ----------------
__global__ void prep_eg(P p) {
  const int wg = blockIdx.x;             // 8192 = 64 m-blocks x 128 n-tiles
  const int bn = wg & 127, bm = wg >> 7;
  const int tid = threadIdx.x, wave = tid >> 6, lane = tid & 63;
  const int arow = lane & 15, kq = (lane >> 4) * 8;
  const int m0 = bm * 64 + wave * 16;    // flat row in [0,4096)
  const int n0 = bn * 16;
  const int token = p.tok[m0 + arow];
  const float* A = p.emb + (size_t)token * 512;
  const unsigned short* Bp = p.W0E + (size_t)(n0 + arow) * 512 + kq;
  f32x4 acc = zero4();
  for (int kk = 0; kk < 512; kk += 32) {
    bf16x8 ah, al;
    splitA(A + kk + kq, ah, al);
    acc = mfma3(ah, al, ldb(Bp + kk), ldb(Bp + NW0E + kk), acc);
  }
  const int r0 = m0 + (lane >> 4) * 4;
  const float bb = p.b0[n0 + arow];
#pragma unroll
  for (int r = 0; r < 4; ++r)
    p.EGb[(size_t)(r0 + r) * 2048 + n0 + arow] = acc[r] + bb;
}

// ---------------- persistent decoder: 4 independent groups x 64 WGs ----------------
__global__ void __launch_bounds__(256) decoder_main(P p) {
  const int wg = blockIdx.x, tid = threadIdx.x;
  const int wave = tid >> 6, lane = tid & 63;
  const int arow = lane & 15;            // fragment row (A: m, B: n)
  const int kq = (lane >> 4) * 8;
  const int g = wg >> 6;                 // group 0..3 (owns batches 16g..16g+16)
  const int u = wg & 63;                 // WG index within group
  unsigned nb = 0;                       // group-barrier epoch

  __shared__ unsigned short MbHi[32][512]; // 32 KB: mbank slice hi (bf16)
  __shared__ unsigned short MbLo[32][512]; // 32 KB: mbank slice lo (bf16 residual)
  __shared__ float Aslab[16][516];         // 33 KB: staged GEMM A operand
  __shared__ float exch[4][16][16];        // gate exchange / proj reduce
  __shared__ float scl[128];
  __shared__ float pl[128];
  __shared__ float prj[1024];              // [ctx | h1] for folded projection

  const int attb = (g << 4) + (u >> 2);  // this WG's attention batch
  const int attq = u & 3;                // quarter within batch

  // pin mbank slice in LDS as exact hi+lo bf16 split (f32-equivalent)
  for (int idx = tid; idx < 32 * 512; idx += 256) {
    int r = idx >> 9, c = idx & 511;
    float v = p.mbank[(size_t)(attb * 128 + attq * 32 + r) * 512 + c];
    unsigned short hb = f2bf(v);
    MbHi[r][c] = hb;
    MbLo[r][c] = f2bf(v - bf2f(hb));
  }
  // pin this wave's 8 score-matrix rows in registers
  float mwreg[8][8];
  {
    const float* mwb = p.Mw + (size_t)(attb * 128 + attq * 32 + wave * 8) * 512 + lane * 8;
#pragma unroll
    for (int i = 0; i < 8; ++i) {
      float4 a = *(const float4*)(mwb + i * 512);
      float4 b = *(const float4*)(mwb + i * 512 + 4);
      mwreg[i][0] = a.x; mwreg[i][1] = a.y; mwreg[i][2] = a.z; mwreg[i][3] = a.w;
      mwreg[i][4] = b.x; mwreg[i][5] = b.y; mwreg[i][6] = b.z; mwreg[i][7] = b.w;
    }
  }

  const int w2 = (u < 32) ? u : u - 32;
  const int strip = w2;                  // 16-col strip (32 strips = 512 cols)
  const int gate = wave;
  const int colj = strip * 16 + arow;
  const int rowbase = g * 16 * 512;      // group's 16 batch rows

  // group barrier: 64 per-WG epoch slots, one-wave parallel poll
  unsigned* slots = p.flag + 128 + g * 128;
  auto gbar = [&]() {
    ++nb;
    asm volatile("s_waitcnt vmcnt(0)" ::: "memory");
    __syncthreads();
    if (tid == 0) ATS(&slots[u], nb);
    for (;;) {
      unsigned v = (tid < 64) ? ATL(&slots[tid]) : nb;
      if (__syncthreads_count((int)(v < nb)) == 0) break;
    }
  };
  auto fsync = [&](unsigned* f, unsigned tgt) {
    asm volatile("s_waitcnt vmcnt(0)" ::: "memory");
    __syncthreads();
    if (tid == 0) {
      ATA(f, 1u);
      while (ATL(f) < tgt) __builtin_amdgcn_s_sleep(1);
    }
    __syncthreads();
  };

  // device-scope (sc1) staging: coherent at LLC
  auto stageC = [&](const float* base) { // [16][512] row-major -> Aslab
    __syncthreads();
    float4 v[8];
    const float* ap[8];
#pragma unroll
    for (int j = 0; j < 8; ++j) {
      int idx = tid * 4 + j * 1024;
      ap[j] = base + (idx >> 9) * 512 + (idx & 511);
    }
#pragma unroll
    for (int j = 0; j < 8; ++j)
      asm volatile("global_load_dwordx4 %0, %1, off sc1" : "=v"(v[j]) : "v"(ap[j]));
    asm volatile("s_waitcnt vmcnt(0)" ::: "memory");
    __builtin_amdgcn_sched_barrier(0);
#pragma unroll
    for (int j = 0; j < 8; ++j) {
      int idx = tid * 4 + j * 1024;
      *(float4*)&Aslab[idx >> 9][idx & 511] = v[j];
    }
    __syncthreads();
  };
  auto gemm_half = [&](const unsigned short* whi, const unsigned short* wlo,
                       f32x4 acc) {
#pragma unroll 4
    for (int kk = 0; kk < 512; kk += 32) {
      bf16x8 ah, al;
      splitA(&Aslab[arow][kk + kq], ah, al);
      acc = mfma3(ah, al, ldb(whi + kk), ldb(wlo + kk), acc);
    }
    return acc;
  };

  for (int t = 0; t < TT; ++t) {
    const float* h0c = p.h0buf + (t & 1) * (BB * HH);
    float* h0n = p.h0buf + ((t + 1) & 1) * (BB * HH);

    // ---- P1: gates0+cell0 (u<32) || h1_prev @ Whh1 + b1 (u>=32) ----
    if (u < 32) {
      const size_t wr = (size_t)(gate * 512 + colj) * 1024;
      // hoist EGb loads so their latency hides under staging + GEMM
      const float* eg =
          p.EGb + ((size_t)(t * 64 + g * 16)) * 2048 + gate * 512 + colj;
      float egv[4];
#pragma unroll
      for (int r = 0; r < 4; ++r) egv[r] = eg[((lane >> 4) * 4 + r) * 2048];
      f32x4 acc = zero4();
      stageC(p.feed + rowbase);
      acc = gemm_half(p.W0R + wr + kq, p.W0R + NW0R + wr + kq, acc);
      stageC(h0c + rowbase);
      acc = gemm_half(p.W0R + wr + 512 + kq, p.W0R + NW0R + wr + 512 + kq, acc);
#pragma unroll
      for (int r = 0; r < 4; ++r) {
        acc[r] += egv[r];
        exch[gate][(lane >> 4) * 4 + r][arow] = acc[r];
      }
      __syncthreads();
      {
        int br = tid >> 4, nc = tid & 15;
        int idx = rowbase + br * 512 + strip * 16 + nc;
        float iv = sigm(exch[0][br][nc]);
        float fv = sigm(exch[1][br][nc]);
        float gv = tanhf(exch[2][br][nc]);
        float ov = sigm(exch[3][br][nc]);
        float cn = fv * p.c0s[idx] + iv * gv;
        p.c0s[idx] = cn;
        float hv = ov * tanhf(cn);
        ATS(&h0n[idx], hv);
        if (t == TT - 1) { p.out_cf[idx] = cn; p.out_hf[idx] = hv; }
      }
    } else {
      const size_t wr = (size_t)(gate * 512 + colj) * 512;
      stageC(p.h1s + rowbase);
      f32x4 acc = gemm_half(p.Whh1 + wr + kq, p.Whh1 + NW1 + wr + kq, zero4());
      const float bb = p.b1[gate * 512 + colj];
#pragma unroll
      for (int r = 0; r < 4; ++r)
        ATS(&p.part1[(g * 16 + (lane >> 4) * 4 + r) * 2048 + gate * 512 + colj],
            acc[r] + bb);
    }
    gbar();

    // ---- P2: gates1(ih part) + part1 + cell1 (u<32); ctx zero (u>=32) ----
    if (u < 32) {
      const size_t wr = (size_t)(gate * 512 + colj) * 512;
      // hoist part1 loads (visible after gbar) ahead of staging
      float pv[4];
#pragma unroll
      for (int r = 0; r < 4; ++r)
        pv[r] = ATL(&p.part1[(g * 16 + (lane >> 4) * 4 + r) * 2048 +
                             gate * 512 + colj]);
      stageC(h0n + rowbase);
      f32x4 acc = gemm_half(p.Wih1 + wr + kq, p.Wih1 + NW1 + wr + kq, zero4());
#pragma unroll
      for (int r = 0; r < 4; ++r) {
        acc[r] += pv[r];
        exch[gate][(lane >> 4) * 4 + r][arow] = acc[r];
      }
      __syncthreads();
      {
        int br = tid >> 4, nc = tid & 15;
        int idx = rowbase + br * 512 + strip * 16 + nc;
        float iv = sigm(exch[0][br][nc]);
        float fv = sigm(exch[1][br][nc]);
        float gv = tanhf(exch[2][br][nc]);
        float ov = sigm(exch[3][br][nc]);
        float cn = fv * p.c1s[idx] + iv * gv;
        p.c1s[idx] = cn;
        float hv = ov * tanhf(cn);
        ATS(&p.h1s[idx], hv);
        if (t == TT - 1) { p.out_cf[BB * HH + idx] = cn; p.out_hf[BB * HH + idx] = hv; }
      }
    } else {
      int base = g * 8192 + (u - 32) * 256 + tid;
      ATS(&p.ctx[base], 0.f);
    }
    gbar();

    // ---- P3: attention + folded output projection (4 WGs per batch) ----
    {
      float h8[8];
      {
        const float* hp = p.h1s + attb * 512 + lane * 8;
        float4 a, c;
        asm volatile("global_load_dwordx4 %0, %1, off sc1" : "=v"(a) : "v"(hp));
        asm volatile("global_load_dwordx4 %0, %1, off sc1" : "=v"(c) : "v"(hp + 4));
        asm volatile("s_waitcnt vmcnt(0)" ::: "memory");
        __builtin_amdgcn_sched_barrier(0);
        h8[0] = a.x; h8[1] = a.y; h8[2] = a.z; h8[3] = a.w;
        h8[4] = c.x; h8[5] = c.y; h8[6] = c.z; h8[7] = c.w;
      }
#pragma unroll
      for (int i = 0; i < 8; ++i) {
        const int sl = wave * 8 + i;
        float d = h8[0] * mwreg[i][0] + h8[1] * mwreg[i][1] +
                  h8[2] * mwreg[i][2] + h8[3] * mwreg[i][3] +
                  h8[4] * mwreg[i][4] + h8[5] * mwreg[i][5] +
                  h8[6] * mwreg[i][6] + h8[7] * mwreg[i][7];
#pragma unroll
        for (int o = 32; o; o >>= 1) d += __shfl_xor(d, o);
        if (lane == 0) ATS(&p.scg[attb * 128 + attq * 32 + sl], d);
      }
      fsync(&p.flag[attb], 4u * (unsigned)(t + 1));   // scores ready
      if (tid < 128) scl[tid] = ATL(&p.scg[attb * 128 + tid]);
      __syncthreads();
      if (wave == 0) {
        const int lenb = p.len[attb];
        float s0 = (lane < lenb) ? scl[lane] : -__builtin_inff();
        float s1 = (lane + 64 < lenb) ? scl[lane + 64] : -__builtin_inff();
        float mx = fmaxf(s0, s1);
#pragma unroll
        for (int o = 32; o; o >>= 1) mx = fmaxf(mx, __shfl_xor(mx, o));
        float e0 = (lane < lenb) ? __expf(s0 - mx) : 0.f;
        float e1 = (lane + 64 < lenb) ? __expf(s1 - mx) : 0.f;
        float sm = e0 + e1;
#pragma unroll
        for (int o = 32; o; o >>= 1) sm += __shfl_xor(sm, o);
        float inv = 1.f / sm;
        pl[lane] = e0 * inv; pl[lane + 64] = e1 * inv;
        if (attq == 0) {
          float* ao = p.out_attn + ((size_t)t * BB + attb) * SS;
          ao[lane] = e0 * inv; ao[lane + 64] = e1 * inv;
        }
        // stash h1 into prj[512..1024) (wave0 holds full h1[attb] in h8)
        *(float4*)&prj[512 + lane * 8]     = make_float4(h8[0], h8[1], h8[2], h8[3]);
        *(float4*)&prj[512 + lane * 8 + 4] = make_float4(h8[4], h8[5], h8[6], h8[7]);
      }
      __syncthreads();
      {
        const int h2 = tid * 2;
        float ca = 0.f, cb = 0.f;
#pragma unroll 4
        for (int s = 0; s < 32; ++s) {
          float ps = pl[attq * 32 + s];
          unsigned vh = *(const unsigned*)&MbHi[s][h2];
          unsigned vl = *(const unsigned*)&MbLo[s][h2];
          ca += ps * (bf2f((unsigned short)(vh & 0xffffu)) +
                      bf2f((unsigned short)(vl & 0xffffu)));
          cb += ps * (bf2f((unsigned short)(vh >> 16)) +
                      bf2f((unsigned short)(vl >> 16)));
        }
        atomicAdd(&p.ctx[attb * 512 + h2], ca);
        atomicAdd(&p.ctx[attb * 512 + h2 + 1], cb);
      }
      fsync(&p.flag[64 + attb], 4u * (unsigned)(t + 1));  // ctx ready
      {
        prj[tid * 2]     = ATL(&p.ctx[attb * 512 + tid * 2]);
        prj[tid * 2 + 1] = ATL(&p.ctx[attb * 512 + tid * 2 + 1]);
      }
      __syncthreads();
      // projection: out[j] = tanh(sum_k prj[k] * WoutT[k][j]), j = attq*128..+128
      {
        const int jc = attq * 128 + (tid & 127);
        const int kh = tid >> 7;                 // k-half 0/1
        const float* wt = p.WoutT + jc;
        float d = 0.f;
#pragma unroll 8
        for (int k = kh * 512; k < kh * 512 + 512; ++k)
          d = fmaf(prj[k], wt[(size_t)k * 512], d);
        float* exf = (float*)exch;
        if (kh == 1) exf[tid - 128] = d;
        __syncthreads();
        if (kh == 0) {
          d += exf[tid];
          float v = tanhf(d);
          p.out_dec[(size_t)t * BB * HH + attb * 512 + jc] = v;
          ATS(&p.feed[attb * 512 + jc], v);
        }
      }
    }
    gbar();
  }
}

extern "C" void kernel_launch(void* const* d_in, const int* in_sizes, int n_in,
                              void* d_out, int out_size, void* d_ws, size_t ws_size,
                              hipStream_t stream) {
  P p;
  p.tok   = (const int*)d_in[0];
  p.mbank = (const float*)d_in[1];
  p.len   = (const int*)d_in[2];
  p.h0_in = (const float*)d_in[3];
  p.c0_in = (const float*)d_in[4];
  p.emb   = (const float*)d_in[5];
  p.w_ih0 = (const float*)d_in[6];
  p.w_hh0 = (const float*)d_in[7];
  p.b_ih0 = (const float*)d_in[8];
  p.b_hh0 = (const float*)d_in[9];
  p.w_ih1 = (const float*)d_in[10];
  p.w_hh1 = (const float*)d_in[11];
  p.b_ih1 = (const float*)d_in[12];
  p.b_hh1 = (const float*)d_in[13];
  p.w_in  = (const float*)d_in[14];
  p.w_out = (const float*)d_in[15];

  float* out = (float*)d_out;
  p.out_dec  = out;
  p.out_attn = out + (size_t)TT * BB * HH;
  p.out_hf   = out + (size_t)TT * BB * HH + (size_t)TT * BB * SS;
  p.out_cf   = p.out_hf + 2 * BB * HH;

  char* w = (char*)d_ws;
  auto alloc = [&](size_t n) { char* r = w; w += (n + 255) & ~(size_t)255; return r; };
  p.W0E   = (unsigned short*)alloc((size_t)NW0E * 2 * 2);
  p.W0R   = (unsigned short*)alloc((size_t)NW0R * 2 * 2);
  p.Wih1  = (unsigned short*)alloc((size_t)NW1 * 2 * 2);
  p.Whh1  = (unsigned short*)alloc((size_t)NW1 * 2 * 2);
  p.WinT  = (unsigned short*)alloc((size_t)NWI * 2 * 2);
  p.WoutT = (float*)alloc((size_t)NWO * 4);
  p.EGb   = (float*)alloc((size_t)4096 * 2048 * 4);
  p.Mw    = (float*)alloc((size_t)BB * SS * HH * 4);
  p.b0    = (float*)alloc(2048 * 4);
  p.b1    = (float*)alloc(2048 * 4);
  p.h0buf = (float*)alloc((size_t)2 * BB * HH * 4);
  p.h1s   = (float*)alloc((size_t)BB * HH * 4);
  p.c0s   = (float*)alloc((size_t)BB * HH * 4);
  p.c1s   = (float*)alloc((size_t)BB * HH * 4);
  p.feed  = (float*)alloc((size_t)BB * HH * 4);
  p.part1 = (float*)alloc((size_t)BB * GG * 4);
  p.ctx   = (float*)alloc((size_t)BB * HH * 4);
  p.scg   = (float*)alloc((size_t)BB * SS * 4);
  p.flag  = (unsigned int*)alloc(1024 * 4);

  hipLaunchKernelGGL(prep_weights, dim3(4096), dim3(256), 0, stream, p);
  hipLaunchKernelGGL(prep_mw, dim3(4096), dim3(256), 0, stream, p);
  hipLaunchKernelGGL(prep_eg, dim3(8192), dim3(256), 0, stream, p);

  // decoder_main uses only custom barriers (no cooperative-groups features).
  // Cooperative launch fails SILENTLY for some binaries (VGPR-dependent);
  // check it and fall back to a plain launch (256 WGs x 1/CU are co-resident).
  void* args[] = {(void*)&p};
  hipError_t ce = hipLaunchCooperativeKernel((void*)decoder_main, dim3(256),
                                             dim3(256), args, 0, stream);
  if (ce != hipSuccess) {
    (void)hipGetLastError();   // clear sticky error state
    hipLaunchKernelGGL(decoder_main, dim3(256), dim3(256), 0, stream, p);
  }
}

// Round 19
// 3353.276 us; speedup vs baseline: 1.0625x; 1.0625x over previous
//
#include <hip/hip_runtime.h>
#include <hip/hip_bf16.h>

typedef __bf16 bf16x8 __attribute__((ext_vector_type(8)));
typedef unsigned short u16x8 __attribute__((ext_vector_type(8)));
typedef float f32x4 __attribute__((ext_vector_type(4)));

constexpr int TT = 64;   // timesteps
constexpr int BB = 64;   // batch
constexpr int SS = 128;  // memory length
constexpr int HH = 512;  // hidden
constexpr int GG = 2048; // 4*H

// weight sizes (elements); hi at [0], lo at [N]
constexpr int NW0E = 2048 * 512;
constexpr int NW0R = 2048 * 1024;
constexpr int NW1  = 2048 * 512;
constexpr int NWO  = 512 * 1024;
constexpr int NWI  = 512 * 512;

struct P {
  const int* tok; const float* mbank; const int* len;
  const float* h0_in; const float* c0_in; const float* emb;
  const float* w_ih0; const float* w_hh0; const float* b_ih0; const float* b_hh0;
  const float* w_ih1; const float* w_hh1; const float* b_ih1; const float* b_hh1;
  const float* w_in; const float* w_out;
  float* out_dec; float* out_attn; float* out_hf; float* out_cf;
  unsigned short *W0E, *W0R, *Wih1, *Whh1, *Wout, *WinT;
  float *EGb;                             // f32: score-path precision
  float *Mw;
  float *b0, *b1, *h0buf, *h1s, *c0s, *c1s, *feed, *part1, *ctx, *scg;
  unsigned int* flag;  // [0..63] score flags, [128 + g*128 + u] barrier slots
};

__device__ __forceinline__ unsigned short f2bf(float f) {
  unsigned int u = __builtin_bit_cast(unsigned int, f);
  return (unsigned short)((u + 0x7fffu + ((u >> 16) & 1u)) >> 16);
}
__device__ __forceinline__ float bf2f(unsigned short h) {
  return __builtin_bit_cast(float, ((unsigned int)h) << 16);
}
__device__ __forceinline__ bf16x8 ldb(const unsigned short* p) {
  return __builtin_bit_cast(bf16x8, *(const u16x8*)p);
}
__device__ __forceinline__ f32x4 mfma_(bf16x8 a, bf16x8 b, f32x4 c) {
  return __builtin_amdgcn_mfma_f32_16x16x32_bf16(a, b, c, 0, 0, 0);
}
__device__ __forceinline__ float sigm(float x) { return 1.f / (1.f + __expf(-x)); }
__device__ __forceinline__ f32x4 zero4() { f32x4 z = {0.f, 0.f, 0.f, 0.f}; return z; }

#define ATL(pp) __hip_atomic_load((pp), __ATOMIC_RELAXED, __HIP_MEMORY_SCOPE_AGENT)
#define ATS(pp, vv) __hip_atomic_store((pp), (vv), __ATOMIC_RELAXED, __HIP_MEMORY_SCOPE_AGENT)
#define ATA(pp, vv) __hip_atomic_fetch_add((pp), (vv), __ATOMIC_RELAXED, __HIP_MEMORY_SCOPE_AGENT)

__device__ __forceinline__ void splitA(const float* s, bf16x8& hi, bf16x8& lo) {
  float4 a0 = *(const float4*)s;
  float4 a1 = *(const float4*)(s + 4);
  float v[8] = {a0.x, a0.y, a0.z, a0.w, a1.x, a1.y, a1.z, a1.w};
  u16x8 h, l;
#pragma unroll
  for (int j = 0; j < 8; ++j) {
    unsigned short hb = f2bf(v[j]);
    h[j] = hb;
    l[j] = f2bf(v[j] - bf2f(hb));
  }
  hi = __builtin_bit_cast(bf16x8, h);
  lo = __builtin_bit_cast(bf16x8, l);
}
__device__ __forceinline__ f32x4 mfma3(bf16x8 ah, bf16x8 al, bf16x8 bh, bf16x8 bl, f32x4 c) {
  c = mfma_(al, bh, c);
  c = mfma_(ah, bl, c);
  c = mfma_(ah, bh, c);
  return c;
}

// ---------------- prep: weight split / transpose / state init ----------------
__global__ void prep_weights(P p) {
  constexpr int TOT = NW0E + NW0R + NW1 + NW1 + NWO + NWI + 2048 + 2048 +
                      32768 * 5 + 8192 + 1024;
  for (int i = blockIdx.x * blockDim.x + threadIdx.x; i < TOT;
       i += gridDim.x * blockDim.x) {
    int j = i;
    float v; unsigned short* dst; int N;
    if (j < NW0E) {              // emb part of w_ih0: [2048][512]
      int n = j >> 9, k = j & 511;
      v = p.w_ih0[n * 1024 + k];
      dst = p.W0E; N = NW0E; goto split;
    }
    j -= NW0E;
    if (j < NW0R) {              // [feed | h] : [2048][1024]
      int n = j >> 10, k = j & 1023;
      v = (k < 512) ? p.w_ih0[n * 1024 + 512 + k] : p.w_hh0[n * 512 + (k - 512)];
      dst = p.W0R; N = NW0R; goto split;
    }
    j -= NW0R;
    if (j < NW1) { v = p.w_ih1[j]; dst = p.Wih1; N = NW1; goto split; }
    j -= NW1;
    if (j < NW1) { v = p.w_hh1[j]; dst = p.Whh1; N = NW1; goto split; }
    j -= NW1;
    if (j < NWO) { v = p.w_out[j]; dst = p.Wout; N = NWO; goto split; }
    j -= NWO;
    if (j < NWI) {               // WinT[n][k] = w_in[k][n]
      int n = j >> 9, q = j & 511;
      v = p.w_in[q * 512 + n];
      dst = p.WinT; N = NWI; goto split;
    }
    j -= NWI;
    if (j < 2048) { p.b0[j] = p.b_ih0[j] + p.b_hh0[j]; continue; }
    j -= 2048;
    if (j < 2048) { p.b1[j] = p.b_ih1[j] + p.b_hh1[j]; continue; }
    j -= 2048;
    if (j < 32768) { p.h0buf[j] = p.h0_in[j]; continue; }
    j -= 32768;
    if (j < 32768) { p.h1s[j] = p.h0_in[32768 + j]; continue; }
    j -= 32768;
    if (j < 32768) { p.c0s[j] = p.c0_in[j]; continue; }
    j -= 32768;
    if (j < 32768) { p.c1s[j] = p.c0_in[32768 + j]; continue; }
    j -= 32768;
    if (j < 32768) { p.feed[j] = 0.f; continue; }
    j -= 32768;
    if (j < 8192) { p.scg[j] = 0.f; continue; }
    j -= 8192;
    p.flag[j] = 0u;
    continue;
  split:
    {
      unsigned short hb = f2bf(v);
      dst[j] = hb;
      dst[N + j] = f2bf(v - bf2f(hb));
    }
  }
}

// ---------------- prep: Mw[b,s,n] = sum_k M[b,s,k] * w_in[k,n]  (f32) ----------------
__global__ void prep_mw(P p) {
  const int wg = blockIdx.x;             // 4096 = 128 m-blocks x 32 n-tiles
  const int bm = wg & 127, bn = wg >> 7;
  const int tid = threadIdx.x, wave = tid >> 6, lane = tid & 63;
  const int arow = lane & 15, kq = (lane >> 4) * 8;
  const int m0 = bm * 64 + wave * 16;
  const int n0 = bn * 16;
  const float* A = p.mbank + (size_t)(m0 + arow) * HH;
  const unsigned short* Bp = p.WinT + (size_t)(n0 + arow) * HH + kq;
  f32x4 acc = zero4();
  for (int kk = 0; kk < HH; kk += 32) {
    bf16x8 ah, al;
    splitA(A + kk + kq, ah, al);
    acc = mfma3(ah, al, ldb(Bp + kk), ldb(Bp + NWI + kk), acc);
  }
  const int r0 = m0 + (lane >> 4) * 4;
#pragma unroll
  for (int r = 0; r < 4; ++r)
    p.Mw[(size_t)(r0 + r) * HH + n0 + arow] = acc[r];
}

// ---------------- prep: EGb[t*64+b, n] = emb[tok] @ W0E^T + b0  (f32) ----------------
__global__ void prep_eg(P p) {
  const int wg = blockIdx.x;             // 8192 = 64 m-blocks x 128 n-tiles
  const int bn = wg & 127, bm = wg >> 7;
  const int tid = threadIdx.x, wave = tid >> 6, lane = tid & 63;
  const int arow = lane & 15, kq = (lane >> 4) * 8;
  const int m0 = bm * 64 + wave * 16;    // flat row in [0,4096)
  const int n0 = bn * 16;
  const int token = p.tok[m0 + arow];
  const float* A = p.emb + (size_t)token * 512;
  const unsigned short* Bp = p.W0E + (size_t)(n0 + arow) * 512 + kq;
  f32x4 acc = zero4();
  for (int kk = 0; kk < 512; kk += 32) {
    bf16x8 ah, al;
    splitA(A + kk + kq, ah, al);
    acc = mfma3(ah, al, ldb(Bp + kk), ldb(Bp + NW0E + kk), acc);
  }
  const int r0 = m0 + (lane >> 4) * 4;
  const float bb = p.b0[n0 + arow];
#pragma unroll
  for (int r = 0; r < 4; ++r)
    p.EGb[(size_t)(r0 + r) * 2048 + n0 + arow] = acc[r] + bb;
}

// ---------------- persistent decoder: 4 independent groups x 64 WGs ----------------
__global__ void __launch_bounds__(256) decoder_main(P p) {
  const int wg = blockIdx.x, tid = threadIdx.x;
  const int wave = tid >> 6, lane = tid & 63;
  const int arow = lane & 15;            // fragment row (A: m, B: n)
  const int kq = (lane >> 4) * 8;
  const int g = wg >> 6;                 // group 0..3 (owns batches 16g..16g+16)
  const int u = wg & 63;                 // WG index within group
  unsigned nb = 0;                       // group-barrier epoch

  __shared__ unsigned short MbHi[32][512]; // 32 KB: mbank slice hi (bf16)
  __shared__ unsigned short MbLo[32][512]; // 32 KB: mbank slice lo (bf16 residual)
  __shared__ float Aslab[16][516];         // 33 KB: staged GEMM A operand
  __shared__ float exch[4][16][16];        // gate exchange
  __shared__ float scl[128];
  __shared__ float pl[128];

  const int attb = (g << 4) + (u >> 2);  // this WG's attention batch
  const int attq = u & 3;                // quarter within batch

  // pin mbank slice in LDS as exact hi+lo bf16 split (f32-equivalent)
  for (int idx = tid; idx < 32 * 512; idx += 256) {
    int r = idx >> 9, c = idx & 511;
    float v = p.mbank[(size_t)(attb * 128 + attq * 32 + r) * 512 + c];
    unsigned short hb = f2bf(v);
    MbHi[r][c] = hb;
    MbLo[r][c] = f2bf(v - bf2f(hb));
  }
  // pin this wave's 8 score-matrix rows in registers
  float mwreg[8][8];
  {
    const float* mwb = p.Mw + (size_t)(attb * 128 + attq * 32 + wave * 8) * 512 + lane * 8;
#pragma unroll
    for (int i = 0; i < 8; ++i) {
      float4 a = *(const float4*)(mwb + i * 512);
      float4 b = *(const float4*)(mwb + i * 512 + 4);
      mwreg[i][0] = a.x; mwreg[i][1] = a.y; mwreg[i][2] = a.z; mwreg[i][3] = a.w;
      mwreg[i][4] = b.x; mwreg[i][5] = b.y; mwreg[i][6] = b.z; mwreg[i][7] = b.w;
    }
  }

  const int w2 = (u < 32) ? u : u - 32;
  const int strip = w2;                  // 16-col strip (32 strips = 512 cols)
  const int gate = wave;
  const int colj = strip * 16 + arow;
  const int rowbase = g * 16 * 512;      // group's 16 batch rows

  // group barrier: 64 per-WG epoch slots, one-wave parallel poll (no sleep)
  unsigned* slots = p.flag + 128 + g * 128;
  auto gbar = [&]() {
    ++nb;
    asm volatile("s_waitcnt vmcnt(0)" ::: "memory");
    __syncthreads();
    if (tid == 0) ATS(&slots[u], nb);
    for (;;) {
      unsigned v = (tid < 64) ? ATL(&slots[tid]) : nb;
      if (__syncthreads_count((int)(v < nb)) == 0) break;
    }
  };

  // device-scope (sc1) staging: coherent at LLC
  auto stageC = [&](const float* base) { // [16][512] row-major -> Aslab
    __syncthreads();
    float4 v[8];
    const float* ap[8];
#pragma unroll
    for (int j = 0; j < 8; ++j) {
      int idx = tid * 4 + j * 1024;
      ap[j] = base + (idx >> 9) * 512 + (idx & 511);
    }
#pragma unroll
    for (int j = 0; j < 8; ++j)
      asm volatile("global_load_dwordx4 %0, %1, off sc1" : "=v"(v[j]) : "v"(ap[j]));
    asm volatile("s_waitcnt vmcnt(0)" ::: "memory");
    __builtin_amdgcn_sched_barrier(0);
#pragma unroll
    for (int j = 0; j < 8; ++j) {
      int idx = tid * 4 + j * 1024;
      *(float4*)&Aslab[idx >> 9][idx & 511] = v[j];
    }
    __syncthreads();
  };
  // dual-slab pipeline: issue BOTH slabs' loads, stage A, keep B in regs
  auto stage2_issue = [&](const float* baseA, const float* baseB, float4* vb) {
    __syncthreads();
    float4 va[8];
    const float* apA[8];
    const float* apB[8];
#pragma unroll
    for (int j = 0; j < 8; ++j) {
      int idx = tid * 4 + j * 1024;
      apA[j] = baseA + (idx >> 9) * 512 + (idx & 511);
      apB[j] = baseB + (idx >> 9) * 512 + (idx & 511);
    }
#pragma unroll
    for (int j = 0; j < 8; ++j)
      asm volatile("global_load_dwordx4 %0, %1, off sc1" : "=v"(va[j]) : "v"(apA[j]));
#pragma unroll
    for (int j = 0; j < 8; ++j)
      asm volatile("global_load_dwordx4 %0, %1, off sc1" : "=v"(vb[j]) : "v"(apB[j]));
    asm volatile("s_waitcnt vmcnt(0)" ::: "memory");
    __builtin_amdgcn_sched_barrier(0);
#pragma unroll
    for (int j = 0; j < 8; ++j) {
      int idx = tid * 4 + j * 1024;
      *(float4*)&Aslab[idx >> 9][idx & 511] = va[j];
    }
    __syncthreads();
  };
  auto stage2_commit = [&](const float4* vb) {  // after readers done w/ slab A
    __syncthreads();
#pragma unroll
    for (int j = 0; j < 8; ++j) {
      int idx = tid * 4 + j * 1024;
      *(float4*)&Aslab[idx >> 9][idx & 511] = vb[j];
    }
    __syncthreads();
  };
  auto gemm_half = [&](const unsigned short* whi, const unsigned short* wlo,
                       f32x4 acc) {
#pragma unroll 4
    for (int kk = 0; kk < 512; kk += 32) {
      bf16x8 ah, al;
      splitA(&Aslab[arow][kk + kq], ah, al);
      acc = mfma3(ah, al, ldb(whi + kk), ldb(wlo + kk), acc);
    }
    return acc;
  };

  for (int t = 0; t < TT; ++t) {
    const float* h0c = p.h0buf + (t & 1) * (BB * HH);
    float* h0n = p.h0buf + ((t + 1) & 1) * (BB * HH);

    // ---- P1: gates0+cell0 (u<32) || h1_prev @ Whh1 + b1 (u>=32) ----
    if (u < 32) {
      const size_t wr = (size_t)(gate * 512 + colj) * 1024;
      // hoist EGb loads (plain loads precede the staging asm -> issued early)
      const float* eg =
          p.EGb + ((size_t)(t * 64 + g * 16)) * 2048 + gate * 512 + colj;
      float egv[4];
#pragma unroll
      for (int r = 0; r < 4; ++r) egv[r] = eg[((lane >> 4) * 4 + r) * 2048];
      // dual-slab: feed staged now, h0c kept in regs over GEMM-1
      float4 vb[8];
      stage2_issue(p.feed + rowbase, h0c + rowbase, vb);
      f32x4 acc = gemm_half(p.W0R + wr + kq, p.W0R + NW0R + wr + kq, zero4());
      stage2_commit(vb);
      acc = gemm_half(p.W0R + wr + 512 + kq, p.W0R + NW0R + wr + 512 + kq, acc);
#pragma unroll
      for (int r = 0; r < 4; ++r) {
        acc[r] += egv[r];
        exch[gate][(lane >> 4) * 4 + r][arow] = acc[r];
      }
      __syncthreads();
      {
        int br = tid >> 4, nc = tid & 15;
        int idx = rowbase + br * 512 + strip * 16 + nc;
        float iv = sigm(exch[0][br][nc]);
        float fv = sigm(exch[1][br][nc]);
        float gv = tanhf(exch[2][br][nc]);
        float ov = sigm(exch[3][br][nc]);
        float cn = fv * p.c0s[idx] + iv * gv;
        p.c0s[idx] = cn;
        float hv = ov * tanhf(cn);
        ATS(&h0n[idx], hv);
        if (t == TT - 1) { p.out_cf[idx] = cn; p.out_hf[idx] = hv; }
      }
    } else {
      const size_t wr = (size_t)(gate * 512 + colj) * 512;
      stageC(p.h1s + rowbase);
      f32x4 acc = gemm_half(p.Whh1 + wr + kq, p.Whh1 + NW1 + wr + kq, zero4());
      const float bb = p.b1[gate * 512 + colj];
#pragma unroll
      for (int r = 0; r < 4; ++r)
        ATS(&p.part1[(g * 16 + (lane >> 4) * 4 + r) * 2048 + gate * 512 + colj],
            acc[r] + bb);
    }
    gbar();

    // ---- P2: gates1(ih part) + part1 + cell1 (u<32); ctx zero (u>=32) ----
    if (u < 32) {
      const size_t wr = (size_t)(gate * 512 + colj) * 512;
      // hoist part1 loads (visible after gbar) ahead of staging
      float pv[4];
#pragma unroll
      for (int r = 0; r < 4; ++r)
        pv[r] = ATL(&p.part1[(g * 16 + (lane >> 4) * 4 + r) * 2048 +
                             gate * 512 + colj]);
      stageC(h0n + rowbase);
      f32x4 acc = gemm_half(p.Wih1 + wr + kq, p.Wih1 + NW1 + wr + kq, zero4());
#pragma unroll
      for (int r = 0; r < 4; ++r) {
        acc[r] += pv[r];
        exch[gate][(lane >> 4) * 4 + r][arow] = acc[r];
      }
      __syncthreads();
      {
        int br = tid >> 4, nc = tid & 15;
        int idx = rowbase + br * 512 + strip * 16 + nc;
        float iv = sigm(exch[0][br][nc]);
        float fv = sigm(exch[1][br][nc]);
        float gv = tanhf(exch[2][br][nc]);
        float ov = sigm(exch[3][br][nc]);
        float cn = fv * p.c1s[idx] + iv * gv;
        p.c1s[idx] = cn;
        float hv = ov * tanhf(cn);
        ATS(&p.h1s[idx], hv);
        if (t == TT - 1) { p.out_cf[BB * HH + idx] = cn; p.out_hf[BB * HH + idx] = hv; }
      }
    } else {
      int base = g * 8192 + (u - 32) * 256 + tid;
      ATS(&p.ctx[base], 0.f);
    }
    gbar();

    // ---- P3: attention (4 WGs per batch; scores from mwreg, ctx from LDS Mb) ----
    {
      float h8[8];
      {
        const float* hp = p.h1s + attb * 512 + lane * 8;
        float4 a, c;
        asm volatile("global_load_dwordx4 %0, %1, off sc1" : "=v"(a) : "v"(hp));
        asm volatile("global_load_dwordx4 %0, %1, off sc1" : "=v"(c) : "v"(hp + 4));
        asm volatile("s_waitcnt vmcnt(0)" ::: "memory");
        __builtin_amdgcn_sched_barrier(0);
        h8[0] = a.x; h8[1] = a.y; h8[2] = a.z; h8[3] = a.w;
        h8[4] = c.x; h8[5] = c.y; h8[6] = c.z; h8[7] = c.w;
      }
#pragma unroll
      for (int i = 0; i < 8; ++i) {
        const int sl = wave * 8 + i;
        float d = h8[0] * mwreg[i][0] + h8[1] * mwreg[i][1] +
                  h8[2] * mwreg[i][2] + h8[3] * mwreg[i][3] +
                  h8[4] * mwreg[i][4] + h8[5] * mwreg[i][5] +
                  h8[6] * mwreg[i][6] + h8[7] * mwreg[i][7];
#pragma unroll
        for (int o = 32; o; o >>= 1) d += __shfl_xor(d, o);
        if (lane == 0) ATS(&p.scg[attb * 128 + attq * 32 + sl], d);
      }
      asm volatile("s_waitcnt vmcnt(0)" ::: "memory");
      __syncthreads();                   // all score stores drained
      if (tid == 0) {
        ATA(&p.flag[attb], 1u);
        const unsigned tgt = 4u * (unsigned)(t + 1);
        while (ATL(&p.flag[attb]) < tgt) { }   // busy spin (no sleep quantum)
      }
      __syncthreads();
      if (tid < 128) scl[tid] = ATL(&p.scg[attb * 128 + tid]);
      __syncthreads();
      if (wave == 0) {
        const int lenb = p.len[attb];
        float s0 = (lane < lenb) ? scl[lane] : -__builtin_inff();
        float s1 = (lane + 64 < lenb) ? scl[lane + 64] : -__builtin_inff();
        float mx = fmaxf(s0, s1);
#pragma unroll
        for (int o = 32; o; o >>= 1) mx = fmaxf(mx, __shfl_xor(mx, o));
        float e0 = (lane < lenb) ? __expf(s0 - mx) : 0.f;
        float e1 = (lane + 64 < lenb) ? __expf(s1 - mx) : 0.f;
        float sm = e0 + e1;
#pragma unroll
        for (int o = 32; o; o >>= 1) sm += __shfl_xor(sm, o);
        float inv = 1.f / sm;
        pl[lane] = e0 * inv; pl[lane + 64] = e1 * inv;
        if (attq == 0) {
          float* ao = p.out_attn + ((size_t)t * BB + attb) * SS;
          ao[lane] = e0 * inv; ao[lane + 64] = e1 * inv;
        }
      }
      __syncthreads();
      {
        const int h2 = tid * 2;
        float ca = 0.f, cb = 0.f;
#pragma unroll 4
        for (int s = 0; s < 32; ++s) {
          float ps = pl[attq * 32 + s];
          unsigned vh = *(const unsigned*)&MbHi[s][h2];
          unsigned vl = *(const unsigned*)&MbLo[s][h2];
          ca += ps * (bf2f((unsigned short)(vh & 0xffffu)) +
                      bf2f((unsigned short)(vl & 0xffffu)));
          cb += ps * (bf2f((unsigned short)(vh >> 16)) +
                      bf2f((unsigned short)(vl >> 16)));
        }
        atomicAdd(&p.ctx[attb * 512 + h2], ca);
        atomicAdd(&p.ctx[attb * 512 + h2 + 1], cb);
      }
    }
    gbar();

    // ---- P4: attn_h = tanh([ctx | h1] @ Wout^T) -> out_dec, feed (u<8) ----
    if (u < 8) {
      const int nstrip = u * 4 + wave;
      const int cj = nstrip * 16 + arow;
      const size_t wr = (size_t)cj * 1024;
      // dual-slab: ctx staged now, h1 kept in regs over GEMM-1
      float4 vb[8];
      stage2_issue(p.ctx + rowbase, p.h1s + rowbase, vb);
      f32x4 acc = gemm_half(p.Wout + wr + kq, p.Wout + NWO + wr + kq, zero4());
      stage2_commit(vb);
      acc = gemm_half(p.Wout + wr + 512 + kq, p.Wout + NWO + wr + 512 + kq, acc);
      float* dec = p.out_dec + (size_t)t * BB * HH;
#pragma unroll
      for (int r = 0; r < 4; ++r) {
        int b = g * 16 + (lane >> 4) * 4 + r;
        float v = tanhf(acc[r]);
        dec[b * 512 + cj] = v;
        ATS(&p.feed[b * 512 + cj], v);
      }
    }
    gbar();
  }
}

extern "C" void kernel_launch(void* const* d_in, const int* in_sizes, int n_in,
                              void* d_out, int out_size, void* d_ws, size_t ws_size,
                              hipStream_t stream) {
  P p;
  p.tok   = (const int*)d_in[0];
  p.mbank = (const float*)d_in[1];
  p.len   = (const int*)d_in[2];
  p.h0_in = (const float*)d_in[3];
  p.c0_in = (const float*)d_in[4];
  p.emb   = (const float*)d_in[5];
  p.w_ih0 = (const float*)d_in[6];
  p.w_hh0 = (const float*)d_in[7];
  p.b_ih0 = (const float*)d_in[8];
  p.b_hh0 = (const float*)d_in[9];
  p.w_ih1 = (const float*)d_in[10];
  p.w_hh1 = (const float*)d_in[11];
  p.b_ih1 = (const float*)d_in[12];
  p.b_hh1 = (const float*)d_in[13];
  p.w_in  = (const float*)d_in[14];
  p.w_out = (const float*)d_in[15];

  float* out = (float*)d_out;
  p.out_dec  = out;
  p.out_attn = out + (size_t)TT * BB * HH;
  p.out_hf   = out + (size_t)TT * BB * HH + (size_t)TT * BB * SS;
  p.out_cf   = p.out_hf + 2 * BB * HH;

  char* w = (char*)d_ws;
  auto alloc = [&](size_t n) { char* r = w; w += (n + 255) & ~(size_t)255; return r; };
  p.W0E   = (unsigned short*)alloc((size_t)NW0E * 2 * 2);
  p.W0R   = (unsigned short*)alloc((size_t)NW0R * 2 * 2);
  p.Wih1  = (unsigned short*)alloc((size_t)NW1 * 2 * 2);
  p.Whh1  = (unsigned short*)alloc((size_t)NW1 * 2 * 2);
  p.Wout  = (unsigned short*)alloc((size_t)NWO * 2 * 2);
  p.WinT  = (unsigned short*)alloc((size_t)NWI * 2 * 2);
  p.EGb   = (float*)alloc((size_t)4096 * 2048 * 4);
  p.Mw    = (float*)alloc((size_t)BB * SS * HH * 4);
  p.b0    = (float*)alloc(2048 * 4);
  p.b1    = (float*)alloc(2048 * 4);
  p.h0buf = (float*)alloc((size_t)2 * BB * HH * 4);
  p.h1s   = (float*)alloc((size_t)BB * HH * 4);
  p.c0s   = (float*)alloc((size_t)BB * HH * 4);
  p.c1s   = (float*)alloc((size_t)BB * HH * 4);
  p.feed  = (float*)alloc((size_t)BB * HH * 4);
  p.part1 = (float*)alloc((size_t)BB * GG * 4);
  p.ctx   = (float*)alloc((size_t)BB * HH * 4);
  p.scg   = (float*)alloc((size_t)BB * SS * 4);
  p.flag  = (unsigned int*)alloc(1024 * 4);

  hipLaunchKernelGGL(prep_weights, dim3(4096), dim3(256), 0, stream, p);
  hipLaunchKernelGGL(prep_mw, dim3(4096), dim3(256), 0, stream, p);
  hipLaunchKernelGGL(prep_eg, dim3(8192), dim3(256), 0, stream, p);

  // decoder_main uses only custom barriers (no cooperative-groups features).
  // Cooperative launch fails SILENTLY for some binaries (VGPR-dependent);
  // check it and fall back to a plain launch (256 WGs x 1/CU are co-resident).
  void* args[] = {(void*)&p};
  hipError_t ce = hipLaunchCooperativeKernel((void*)decoder_main, dim3(256),
                                             dim3(256), args, 0, stream);
  if (ce != hipSuccess) {
    (void)hipGetLastError();   // clear sticky error state
    hipLaunchKernelGGL(decoder_main, dim3(256), dim3(256), 0, stream, p);
  }
}